// Round 12
// baseline (243.888 us; speedup 1.0000x reference)
//
#include <hip/hip_runtime.h>
#include <math.h>

#define HWSZ 4096
#define C_ 256
#define B_ 8

// ws layout (float offsets)
#define M_WS      0          // mask bf16: 8*256*4096 ushort = 4194304 floats
#define XB_WS     4194304    // x bf16 NHWC [b][hw][c]: 4194304 floats
#define WT2_WS    8388608    // (10*65536 + 9*32*256) ushort
#define SMEAN_WS  8753152    // 2048 (f channel sums)
#define SSCALE_WS 8755200    // 2048

typedef __attribute__((ext_vector_type(8))) short short8;
typedef __attribute__((ext_vector_type(4))) float f32x4;

__device__ __forceinline__ uint bfr(float a) {  // f32 -> bf16 bits (RNE)
  uint u = __float_as_uint(a);
  return (u + 0x7fffu + ((u >> 16) & 1u)) >> 16;
}
__device__ __forceinline__ uint pk2(float a, float b) { return bfr(a) | (bfr(b) << 16); }
__device__ __forceinline__ float bff(ushort u) { return __uint_as_float((uint)u << 16); }
__device__ __forceinline__ float lo16(uint u) { return __uint_as_float(u << 16); }
__device__ __forceinline__ float hi16(uint u) { return __uint_as_float(u & 0xffff0000u); }

// ---------------- k0: weights -> bf16 (+ zero smean) ----------------
__global__ __launch_bounds__(256) void k0_weights(
    const float* __restrict__ w_reg, const float* __restrict__ w_mask,
    const float* __restrict__ w_off, const float* __restrict__ w_mod,
    float* __restrict__ ws) {
  int i = blockIdx.x * 256 + threadIdx.x;
  const int nwt = 10 * 65536;
  const int total = nwt + 9 * 32 * 256;   // 729088
  if (i >= total) {
    int z = i - total;
    if (z < 2048) ws[SMEAN_WS + z] = 0.f;
    return;
  }
  float v;
  if (i < 9 * 65536) {
    int kk = i >> 16, o = (i >> 8) & 255, c = i & 255;
    v = w_reg[(o * C_ + c) * 9 + kk];
  } else if (i < nwt) {
    v = w_mask[i - 9 * 65536];
  } else {
    int e = i - nwt;
    int s = e >> 13, r = e & 8191;
    int o2 = r >> 8, c = r & 255;
    if (o2 < 18)      v = w_off[(o2 * C_ + c) * 9 + s];
    else if (o2 < 27) v = w_mod[((o2 - 18) * C_ + c) * 9 + s];
    else              v = 0.f;
  }
  ((ushort*)(ws + WT2_WS))[i] = (ushort)bfr(v);
}

// ---------------- k0b: x NCHW f32 -> NHWC bf16 ----------------
__global__ __launch_bounds__(256) void k0b_nhwc(const float* __restrict__ x,
                                                float* __restrict__ ws) {
  __shared__ float tile[64][65];
  int b = blockIdx.x >> 6, hw0 = (blockIdx.x & 63) << 6;
  int t = threadIdx.x;
  uint* xb = (uint*)(ws + XB_WS) + ((size_t)b << 19);
  int rr = t >> 6, cc = t & 63;
  int e = t & 7, hwp = t >> 3;
  for (int cg = 0; cg < 4; cg++) {
    __syncthreads();
    const float* xp = x + ((size_t)(b * 256 + cg * 64 + rr)) * HWSZ + hw0 + cc;
    #pragma unroll
    for (int r0 = 0; r0 < 64; r0 += 4)
      tile[r0 + rr][cc] = xp[(size_t)r0 * HWSZ];
    __syncthreads();
    #pragma unroll
    for (int h2 = 0; h2 < 2; h2++) {
      int hw_l = h2 * 32 + hwp;
      int c2 = e * 8;
      uint4 val;
      val.x = pk2(tile[c2][hw_l], tile[c2 + 1][hw_l]);
      val.y = pk2(tile[c2 + 2][hw_l], tile[c2 + 3][hw_l]);
      val.z = pk2(tile[c2 + 4][hw_l], tile[c2 + 5][hw_l]);
      val.w = pk2(tile[c2 + 6][hw_l], tile[c2 + 7][hw_l]);
      *(uint4*)&xb[(size_t)(hw0 + hw_l) * 128 + cg * 32 + e * 4] = val;
    }
  }
}

// ---------------- k2: 2-row blocks (1024 thr, 16 waves), weight-stream amortized ----------------
// Block owns (b, h0, h0+1): 128 positions x 256 o. Waves 0-7 -> row h0, 8-15 -> row h0+1;
// wave w: o0 = (w&7)*32. One weight-panel read per tap serves both rows (halves L2 weight
// stream vs 1-row blocks). Phase A: 4 staged-row epochs serve both rows' shift groups +
// mask conv. Phase B: 9 dbuf gather/GEMM epochs. Regs: 32 AGPR + ~64 VGPR <= 128 (1024,4).
// LDS: 128 KB vb dbuf + 18 KB records = 146 KB -> 1 block/CU.
__global__ __launch_bounds__(1024, 4) void k2_fused(
    const float* __restrict__ b_off, const float* __restrict__ b_mod,
    const float* __restrict__ b_reg, const float* __restrict__ b_mask,
    float* __restrict__ ws, float* __restrict__ out) {
  __shared__ uint vb[2][128 * 128];      // 2 x 64 KB: phase A padded rows / phase B P-rows
  __shared__ float omrf[2 * 9 * 64 * 4]; // 18 KB: [row][tap][n]{dy,dx,md,-}

  int bl = ((blockIdx.x & 7) << 5) | (blockIdx.x >> 3);   // XCD k -> image k (256 grid)
  int b = bl >> 5, h0 = (bl & 31) << 1;
  int t = threadIdx.x;
  int lane = t & 63, w = t >> 6;             // wave 0..15
  const int hw = t >> 5;                     // half-wave id 0..31
  const int cl = lane & 31;                  // channel chunk (8 ch)
  const ushort* xb2 = (const ushort*)(ws + XB_WS) + ((size_t)b << 20);
  const ushort* wt2 = (const ushort*)(ws + WT2_WS);
  const ushort* wom = wt2 + 10 * 65536;
  const int fr = lane & 15, fq = lane >> 4;
  const int rowhalf = w >> 3;                // GEMM row (0/1)
  const int wv8 = w & 7;                     // role within row group

  auto widx = [&](int P) -> uint {
    return (uint)P * 128u + (((uint)cl * 4u) ^ ((uint)(P & 7) << 2));
  };
  // stage one padded x row (pcol 0..65 <-> col pcol-1) into vb[buf]
  auto stageRow = [&](int row, int buf) {
    bool rv = ((unsigned)row < 64u);
    for (int pc = hw; pc < 66; pc += 32) {
      int col = pc - 1;
      uint4 v = make_uint4(0, 0, 0, 0);
      if (rv && ((unsigned)col < 64u))
        v = *(const uint4*)(xb2 + ((size_t)(row * 64 + col)) * 256 + cl * 8);
      *(uint4*)&vb[buf][widx(pc)] = v;
    }
  };
  auto makeRecs = [&](int rloc, int kk, int nl, float* wg, int* ix) {
    const float4 rec = *(const float4*)&omrf[((rloc * 9 + kk) * 64 + nl) * 4];
    float dy = rec.x, dx = rec.y, md = rec.z;
    float py = (float)(h0 + rloc + kk / 3 - 1) + dy;
    float px = (float)(nl + kk % 3 - 1) + dx;
    float fy = floorf(py), fx = floorf(px);
    float ly = py - fy, lx = px - fx;
    int y0 = (int)fy, x0 = (int)fx;
    int y1 = y0 + 1, x1 = x0 + 1;
    float vy0 = ((unsigned)y0 < 64u) ? 1.f : 0.f;
    float vy1 = ((unsigned)y1 < 64u) ? 1.f : 0.f;
    float vx0 = ((unsigned)x0 < 64u) ? 1.f : 0.f;
    float vx1 = ((unsigned)x1 < 64u) ? 1.f : 0.f;
    int cy0 = min(max(y0, 0), 63), cy1 = min(max(y1, 0), 63);
    int cx0 = min(max(x0, 0), 63), cx1 = min(max(x1, 0), 63);
    ix[0] = cy0 * 64 + cx0; wg[0] = (1.f - ly) * (1.f - lx) * md * vy0 * vx0;
    ix[1] = cy0 * 64 + cx1; wg[1] = (1.f - ly) * lx * md * vy0 * vx1;
    ix[2] = cy1 * 64 + cx0; wg[2] = ly * (1.f - lx) * md * vy1 * vx0;
    ix[3] = cy1 * 64 + cx1; wg[3] = ly * lx * md * vy1 * vx1;
  };
  auto gatherTap = [&](int kk, int buf) {
    #pragma unroll
    for (int p = 0; p < 4; p++) {
      int P = p * 32 + hw;
      float wg[4]; int ix[4];
      makeRecs(P >> 6, kk, P & 63, wg, ix);
      float a0 = 0.f, a1 = 0.f, a2 = 0.f, a3 = 0.f, a4 = 0.f, a5 = 0.f, a6 = 0.f, a7 = 0.f;
      #pragma unroll
      for (int cr = 0; cr < 4; cr++) {
        uint4 dd = *(const uint4*)(xb2 + (size_t)ix[cr] * 256 + cl * 8);
        float wv = wg[cr];
        a0 = fmaf(wv, lo16(dd.x), a0); a1 = fmaf(wv, hi16(dd.x), a1);
        a2 = fmaf(wv, lo16(dd.y), a2); a3 = fmaf(wv, hi16(dd.y), a3);
        a4 = fmaf(wv, lo16(dd.z), a4); a5 = fmaf(wv, hi16(dd.z), a5);
        a6 = fmaf(wv, lo16(dd.w), a6); a7 = fmaf(wv, hi16(dd.w), a7);
      }
      *(uint4*)&vb[buf][widx(P)] =
          make_uint4(pk2(a0, a1), pk2(a2, a3), pk2(a4, a5), pk2(a6, a7));
    }
  };

  // ======== Phase A: 4 staged rows (h0-1..h0+2) serve both rows' 9 shifts + mask ========
  f32x4 aom = (f32x4)0.f;
  const int m0 = wv8 >> 2, nt0 = wv8 & 3;
  const int o0 = wv8 << 5;
  const int hme = h0 + rowhalf;              // my output row
  f32x4 acc[2][4];                           // mask conv now, deform later
  #pragma unroll
  for (int mt = 0; mt < 2; mt++)
    #pragma unroll
    for (int nt = 0; nt < 4; nt++) acc[mt][nt] = (f32x4)0.f;
  ushort* mws = (ushort*)(ws + M_WS);
  float* sme = ws + SMEAN_WS + b * 256;

  stageRow(h0 - 1, 0);
  __syncthreads();
  for (int e = 0; e < 4; e++) {
    const int buf = e & 1;
    const int g = (rowhalf == 0) ? e : e - 1;          // my shift group for this staged row
    if (g >= 0 && g < 3) {
      const int bnA = nt0 * 16 + fr;
      #pragma unroll
      for (int s3 = 0; s3 < 3; s3++) {
        int s = g * 3 + s3;
        const ushort* wp = wom + (size_t)s * 8192;
        int pcol = bnA + s3;
        uint idxb = (uint)pcol * 128u;
        uint xr = (uint)(pcol & 7) << 2;
        for (int ks = 0; ks < 8; ks++) {
          short8 af = *(const short8*)(wp + (m0 * 16 + fr) * 256 + ks * 32 + fq * 8);
          short8 bf = *(const short8*)&vb[buf][idxb + (((uint)(ks * 16 + fq * 4)) ^ xr)];
          aom = __builtin_amdgcn_mfma_f32_16x16x32_bf16(af, bf, aom, 0, 0, 0);
        }
      }
    }
    // mask 1x1 conv rides my row's staged epoch (row h0 at e=1 buf1; row h0+1 at e=2 buf0)
    if ((rowhalf == 0 && e == 1) || (rowhalf == 1 && e == 2)) {
      const ushort* wt9 = wt2 + (size_t)9 * 65536;
      __builtin_amdgcn_s_setprio(1);
      for (int ks = 0; ks < 8; ks++) {
        short8 af0 = *(const short8*)(wt9 + (o0 + fr) * 256 + ks * 32 + fq * 8);
        short8 af1 = *(const short8*)(wt9 + (o0 + 16 + fr) * 256 + ks * 32 + fq * 8);
        #pragma unroll
        for (int nt = 0; nt < 4; nt++) {
          int pcol = nt * 16 + fr + 1;
          uint idx = (uint)pcol * 128u + (((uint)(ks * 16 + fq * 4)) ^ ((uint)(pcol & 7) << 2));
          short8 bf = *(const short8*)&vb[buf][idx];
          acc[0][nt] = __builtin_amdgcn_mfma_f32_16x16x32_bf16(af0, bf, acc[0][nt], 0, 0, 0);
          acc[1][nt] = __builtin_amdgcn_mfma_f32_16x16x32_bf16(af1, bf, acc[1][nt], 0, 0, 0);
        }
      }
      __builtin_amdgcn_s_setprio(0);
    }
    if (e < 3) stageRow(h0 + e, (e + 1) & 1);
    // row-h0 waves finish at e==2; they do epilogues during e==3 (no GEMM for them)
    if (e == 3 && rowhalf == 0) {
      #pragma unroll
      for (int mt = 0; mt < 2; mt++)
        #pragma unroll
        for (int r = 0; r < 4; r++) {
          int o = o0 + mt * 16 + fq * 4 + r;
          float bm = b_mask[o];
          ushort* mp = mws + (size_t)(b * C_ + o) * HWSZ + hme * 64;
          #pragma unroll
          for (int nt = 0; nt < 4; nt++) {
            float mv = fminf(fmaxf((acc[mt][nt][r] + bm) * (1.f / 6.f) + 0.5f, 0.f), 1.f);
            mp[nt * 16 + fr] = (ushort)bfr(mv);
            acc[mt][nt][r] = 0.f;
          }
        }
      #pragma unroll
      for (int r = 0; r < 4; r++) {
        int o = m0 * 16 + fq * 4 + r;
        int nn = nt0 * 16 + fr;
        if (o < 18) {
          omrf[((0 * 9 + (o >> 1)) * 64 + nn) * 4 + (o & 1)] = aom[r] + b_off[o];
        } else if (o < 27) {
          float v = aom[r] + b_mod[o - 18];
          omrf[((0 * 9 + (o - 18)) * 64 + nn) * 4 + 2] = 2.f / (1.f + expf(-v));
        }
      }
    }
    __syncthreads();
  }
  // row-h0+1 waves: epilogues after their e==3 GEMM
  if (rowhalf == 1) {
    #pragma unroll
    for (int mt = 0; mt < 2; mt++)
      #pragma unroll
      for (int r = 0; r < 4; r++) {
        int o = o0 + mt * 16 + fq * 4 + r;
        float bm = b_mask[o];
        ushort* mp = mws + (size_t)(b * C_ + o) * HWSZ + hme * 64;
        #pragma unroll
        for (int nt = 0; nt < 4; nt++) {
          float mv = fminf(fmaxf((acc[mt][nt][r] + bm) * (1.f / 6.f) + 0.5f, 0.f), 1.f);
          mp[nt * 16 + fr] = (ushort)bfr(mv);
          acc[mt][nt][r] = 0.f;
        }
      }
    #pragma unroll
    for (int r = 0; r < 4; r++) {
      int o = m0 * 16 + fq * 4 + r;
      int nn = nt0 * 16 + fr;
      if (o < 18) {
        omrf[((1 * 9 + (o >> 1)) * 64 + nn) * 4 + (o & 1)] = aom[r] + b_off[o];
      } else if (o < 27) {
        float v = aom[r] + b_mod[o - 18];
        omrf[((1 * 9 + (o - 18)) * 64 + nn) * 4 + 2] = 2.f / (1.f + expf(-v));
      }
    }
  }
  __syncthreads();

  // ======== Phase B: 9 deform taps, dbuf single-barrier, 2 rows per weight stream ========
  gatherTap(0, 0);
  __syncthreads();
  const int Pbase = rowhalf * 64;
  for (int kk = 0; kk < 9; kk++) {
    const int cur = kk & 1;
    const ushort* wtap = wt2 + (size_t)kk * 65536;
    __builtin_amdgcn_s_setprio(1);
    for (int ks = 0; ks < 8; ks++) {
      short8 af0 = *(const short8*)(wtap + (o0 + fr) * 256 + ks * 32 + fq * 8);
      short8 af1 = *(const short8*)(wtap + (o0 + 16 + fr) * 256 + ks * 32 + fq * 8);
      #pragma unroll
      for (int nt = 0; nt < 4; nt++) {
        int P = Pbase + nt * 16 + fr;
        uint idx = (uint)P * 128u + (((uint)(ks * 16 + fq * 4)) ^ ((uint)(P & 7) << 2));
        short8 bf = *(const short8*)&vb[cur][idx];
        acc[0][nt] = __builtin_amdgcn_mfma_f32_16x16x32_bf16(af0, bf, acc[0][nt], 0, 0, 0);
        acc[1][nt] = __builtin_amdgcn_mfma_f32_16x16x32_bf16(af1, bf, acc[1][nt], 0, 0, 0);
      }
    }
    __builtin_amdgcn_s_setprio(0);
    if (kk < 8) {
      gatherTap(kk + 1, cur ^ 1);
      __syncthreads();
    }
  }

  // f epilogue + fused SE partial sums
  #pragma unroll
  for (int mt = 0; mt < 2; mt++)
    #pragma unroll
    for (int r = 0; r < 4; r++) {
      int o = o0 + mt * 16 + fq * 4 + r;
      float bo = b_reg[o];
      float* op = out + (size_t)(b * C_ + o) * HWSZ + hme * 64;
      float so = 0.f;
      #pragma unroll
      for (int nt = 0; nt < 4; nt++) {
        float fv = acc[mt][nt][r] + bo;
        op[nt * 16 + fr] = fv;
        so += fv;
      }
      so += __shfl_xor(so, 1);
      so += __shfl_xor(so, 2);
      so += __shfl_xor(so, 4);
      so += __shfl_xor(so, 8);
      if (fr == 0) atomicAdd(&sme[o], so);
    }
}

// ---------------- k4: SE MLP, one block per batch ----------------
__global__ __launch_bounds__(256) void k4_se(
    const float* __restrict__ w_se1, const float* __restrict__ b_se1,
    const float* __restrict__ w_se2, const float* __restrict__ b_se2,
    float* __restrict__ ws) {
  __shared__ float sm[256];
  __shared__ float s1[64];
  int b = blockIdx.x;
  int t = threadIdx.x;
  sm[t] = ws[SMEAN_WS + b * 256 + t] * (1.f / HWSZ);
  __syncthreads();
  if (t < 64) {
    float a = b_se1[t];
    for (int c = 0; c < 256; c++) a += sm[c] * w_se1[t * 256 + c];
    s1[t] = fmaxf(a, 0.f);
  }
  __syncthreads();
  {
    float a = b_se2[t];
    for (int cr = 0; cr < 64; cr++) a += s1[cr] * w_se2[t * 64 + cr];
    ws[SSCALE_WS + b * 256 + t] = 1.f / (1.f + expf(-a));
  }
}

// ---------------- k5: final combine: out = f*s*m + x ----------------
__global__ __launch_bounds__(256) void k5_final(const float* __restrict__ x,
                                                const float* __restrict__ ws,
                                                float* __restrict__ out) {
  const ushort* mws = (const ushort*)(ws + M_WS);
  int i4 = blockIdx.x * 256 + threadIdx.x;
  const int total = B_ * C_ * HWSZ / 4;
  for (; i4 < total; i4 += gridDim.x * 256) {
    int i = i4 * 4;
    int bc = i >> 12;
    float s = ws[SSCALE_WS + bc];
    float4 f = *(const float4*)&out[i];
    uint2 mu = *(const uint2*)&mws[i];
    float4 xv = *(const float4*)&x[i];
    float4 r;
    r.x = f.x * s * bff((ushort)(mu.x & 0xffffu)) + xv.x;
    r.y = f.y * s * bff((ushort)(mu.x >> 16)) + xv.y;
    r.z = f.z * s * bff((ushort)(mu.y & 0xffffu)) + xv.z;
    r.w = f.w * s * bff((ushort)(mu.y >> 16)) + xv.w;
    *(float4*)&out[i] = r;
  }
}

extern "C" void kernel_launch(void* const* d_in, const int* in_sizes, int n_in,
                              void* d_out, int out_size, void* d_ws, size_t ws_size,
                              hipStream_t stream) {
  const float* x      = (const float*)d_in[0];
  const float* w_off  = (const float*)d_in[1];
  const float* b_off  = (const float*)d_in[2];
  const float* w_mod  = (const float*)d_in[3];
  const float* b_mod  = (const float*)d_in[4];
  const float* w_reg  = (const float*)d_in[5];
  const float* b_reg  = (const float*)d_in[6];
  const float* w_se1  = (const float*)d_in[7];
  const float* b_se1  = (const float*)d_in[8];
  const float* w_se2  = (const float*)d_in[9];
  const float* b_se2  = (const float*)d_in[10];
  const float* w_mask = (const float*)d_in[11];
  const float* b_mask = (const float*)d_in[12];
  float* out = (float*)d_out;
  float* ws  = (float*)d_ws;

  k0_weights<<<dim3(2856), dim3(256), 0, stream>>>(w_reg, w_mask, w_off, w_mod, ws);
  k0b_nhwc<<<dim3(512), dim3(256), 0, stream>>>(x, ws);
  k2_fused<<<dim3(256), dim3(1024), 0, stream>>>(b_off, b_mod, b_reg, b_mask, ws, out);
  k4_se<<<dim3(8), dim3(256), 0, stream>>>(w_se1, b_se1, w_se2, b_se2, ws);
  k5_final<<<dim3(2048), dim3(256), 0, stream>>>(x, ws, out);
}

// Round 13
// 182.940 us; speedup vs baseline: 1.3332x; 1.3332x over previous
//
#include <hip/hip_runtime.h>
#include <hip/hip_fp16.h>
#include <math.h>

#define HWSZ 4096
#define C_ 256
#define B_ 8

// ws layout (float offsets)
#define M_WS      0          // mask f16: 8*256*4096 ushort = 4194304 floats
#define XB_WS     4194304    // x f16 NHWC [b][hw][c]: 4194304 floats
#define WT2_WS    8388608    // (10*65536 + 9*32*256) ushort
#define SMEAN_WS  8753152    // 2048 (f channel sums)
#define SSCALE_WS 8755200    // 2048

typedef __attribute__((ext_vector_type(8))) short short8;
typedef __attribute__((ext_vector_type(4))) float f32x4;

__device__ __forceinline__ ushort f2h(float a) {
  __half h = __float2half(a);
  return *reinterpret_cast<ushort*>(&h);
}
__device__ __forceinline__ uint hpk2(float a, float b) {
  return (uint)f2h(a) | ((uint)f2h(b) << 16);
}
__device__ __forceinline__ uint h2u(__half2 h) { return *reinterpret_cast<uint*>(&h); }
__device__ __forceinline__ __half2 u2h(uint u) { return *reinterpret_cast<__half2*>(&u); }

// ---------------- k0: weights -> f16 (+ zero smean) ----------------
__global__ __launch_bounds__(256) void k0_weights(
    const float* __restrict__ w_reg, const float* __restrict__ w_mask,
    const float* __restrict__ w_off, const float* __restrict__ w_mod,
    float* __restrict__ ws) {
  int i = blockIdx.x * 256 + threadIdx.x;
  const int nwt = 10 * 65536;
  const int total = nwt + 9 * 32 * 256;   // 729088
  if (i >= total) {
    int z = i - total;
    if (z < 2048) ws[SMEAN_WS + z] = 0.f;
    return;
  }
  float v;
  if (i < 9 * 65536) {
    int kk = i >> 16, o = (i >> 8) & 255, c = i & 255;
    v = w_reg[(o * C_ + c) * 9 + kk];
  } else if (i < nwt) {
    v = w_mask[i - 9 * 65536];
  } else {
    int e = i - nwt;
    int s = e >> 13, r = e & 8191;
    int o2 = r >> 8, c = r & 255;
    if (o2 < 18)      v = w_off[(o2 * C_ + c) * 9 + s];
    else if (o2 < 27) v = w_mod[((o2 - 18) * C_ + c) * 9 + s];
    else              v = 0.f;
  }
  ((ushort*)(ws + WT2_WS))[i] = f2h(v);
}

// ---------------- k0b: x NCHW f32 -> NHWC f16 ----------------
__global__ __launch_bounds__(256) void k0b_nhwc(const float* __restrict__ x,
                                                float* __restrict__ ws) {
  __shared__ float tile[64][65];
  int b = blockIdx.x >> 6, hw0 = (blockIdx.x & 63) << 6;
  int t = threadIdx.x;
  uint* xb = (uint*)(ws + XB_WS) + ((size_t)b << 19);
  int rr = t >> 6, cc = t & 63;
  int e = t & 7, hwp = t >> 3;
  for (int cg = 0; cg < 4; cg++) {
    __syncthreads();
    const float* xp = x + ((size_t)(b * 256 + cg * 64 + rr)) * HWSZ + hw0 + cc;
    #pragma unroll
    for (int r0 = 0; r0 < 64; r0 += 4)
      tile[r0 + rr][cc] = xp[(size_t)r0 * HWSZ];
    __syncthreads();
    #pragma unroll
    for (int h2 = 0; h2 < 2; h2++) {
      int hw_l = h2 * 32 + hwp;
      int c2 = e * 8;
      uint4 val;
      val.x = hpk2(tile[c2][hw_l], tile[c2 + 1][hw_l]);
      val.y = hpk2(tile[c2 + 2][hw_l], tile[c2 + 3][hw_l]);
      val.z = hpk2(tile[c2 + 4][hw_l], tile[c2 + 5][hw_l]);
      val.w = hpk2(tile[c2 + 6][hw_l], tile[c2 + 7][hw_l]);
      *(uint4*)&xb[(size_t)(hw0 + hw_l) * 128 + cg * 32 + e * 4] = val;
    }
  }
}

// ---------------- k2: r11 structure, f16 pipeline + depth-2 gather ----------------
// 512 thr (8 waves) per (b,h). Phase A: 3 padded row-copies + 3 GEMM epochs (9 shifts)
// + mask conv riding row-h. Phase B: 9 dbuf gather/GEMM epochs. f16 MFMA; combine via
// v_pk_fma_f16; depth-2 pipelined corner loads (two named reg buffers, static indices).
__global__ __launch_bounds__(512, 4) void k2_fused(
    const float* __restrict__ b_off, const float* __restrict__ b_mod,
    const float* __restrict__ b_reg, const float* __restrict__ b_mask,
    float* __restrict__ ws, float* __restrict__ out) {
  __shared__ uint vbraw[2][66 * 128];   // 67.6 KB: padded rows (A) / dbuf taps (B)
  __shared__ float omrf[9 * 64 * 4];    // 9 KB: per-(tap,n) float4 {dy,dx,md,-}

  int bl = ((blockIdx.x & 7) << 6) | (blockIdx.x >> 3);   // XCD k -> image k
  int b = bl >> 6, h = bl & 63;
  int t = threadIdx.x;
  int lane = t & 63, w = t >> 6;
  const int hwid = t >> 5;                   // half-wave id 0..15
  const int cl = lane & 31;                  // channel chunk (8 ch)
  const ushort* xb2 = (const ushort*)(ws + XB_WS) + ((size_t)b << 20);
  const ushort* wt2 = (const ushort*)(ws + WT2_WS);
  const ushort* wom = wt2 + 10 * 65536;
  const int fr = lane & 15, fq = lane >> 4;

  auto widxP = [&](int pcol) -> uint {
    return (uint)pcol * 128u + (((uint)cl * 4u) ^ ((uint)(pcol & 7) << 2));
  };
  auto stageRow = [&](int row, int buf) {
    bool rv = ((unsigned)row < 64u);
    #pragma unroll
    for (int p = 0; p < 4; p++) {
      int pcol = p * 16 + hwid;
      int col = pcol - 1;
      uint4 v = make_uint4(0, 0, 0, 0);
      if (rv && ((unsigned)col < 64u))
        v = *(const uint4*)(xb2 + ((size_t)(row * 64 + col)) * 256 + cl * 8);
      *(uint4*)&vbraw[buf][widxP(pcol)] = v;
    }
    if (hwid < 2) {
      int pcol = 64 + hwid;
      int col = pcol - 1;
      uint4 v = make_uint4(0, 0, 0, 0);
      if (rv && col < 64)
        v = *(const uint4*)(xb2 + ((size_t)(row * 64 + col)) * 256 + cl * 8);
      *(uint4*)&vbraw[buf][widxP(pcol)] = v;
    }
  };
  // issue one position's records + 4 corner loads
  auto loadPos = [&](int kk, int nl, uint4* d, float* wg) {
    const float4 rec = *(const float4*)&omrf[kk * 256 + nl * 4];
    float dy = rec.x, dx = rec.y, md = rec.z;
    float py = (float)(h + kk / 3 - 1) + dy;
    float px = (float)(nl + kk % 3 - 1) + dx;
    float fy = floorf(py), fx = floorf(px);
    float ly = py - fy, lx = px - fx;
    int y0 = (int)fy, x0 = (int)fx;
    int y1 = y0 + 1, x1 = x0 + 1;
    float vy0 = ((unsigned)y0 < 64u) ? 1.f : 0.f;
    float vy1 = ((unsigned)y1 < 64u) ? 1.f : 0.f;
    float vx0 = ((unsigned)x0 < 64u) ? 1.f : 0.f;
    float vx1 = ((unsigned)x1 < 64u) ? 1.f : 0.f;
    int cy0 = min(max(y0, 0), 63), cy1 = min(max(y1, 0), 63);
    int cx0 = min(max(x0, 0), 63), cx1 = min(max(x1, 0), 63);
    int ix0 = cy0 * 64 + cx0, ix1 = cy0 * 64 + cx1;
    int ix2 = cy1 * 64 + cx0, ix3 = cy1 * 64 + cx1;
    wg[0] = (1.f - ly) * (1.f - lx) * md * vy0 * vx0;
    wg[1] = (1.f - ly) * lx * md * vy0 * vx1;
    wg[2] = ly * (1.f - lx) * md * vy1 * vx0;
    wg[3] = ly * lx * md * vy1 * vx1;
    d[0] = *(const uint4*)(xb2 + (size_t)ix0 * 256 + cl * 8);
    d[1] = *(const uint4*)(xb2 + (size_t)ix1 * 256 + cl * 8);
    d[2] = *(const uint4*)(xb2 + (size_t)ix2 * 256 + cl * 8);
    d[3] = *(const uint4*)(xb2 + (size_t)ix3 * 256 + cl * 8);
  };
  auto combineF16 = [&](const uint4* d, const float* wg) -> uint4 {
    __half2 a0 = __float2half2_rn(0.f), a1 = a0, a2 = a0, a3 = a0;
    #pragma unroll
    for (int cr = 0; cr < 4; cr++) {
      __half2 w2 = __float2half2_rn(wg[cr]);
      a0 = __hfma2(w2, u2h(d[cr].x), a0);
      a1 = __hfma2(w2, u2h(d[cr].y), a1);
      a2 = __hfma2(w2, u2h(d[cr].z), a2);
      a3 = __hfma2(w2, u2h(d[cr].w), a3);
    }
    return make_uint4(h2u(a0), h2u(a1), h2u(a2), h2u(a3));
  };
  // depth-2 pipelined gather: position p+1's loads in flight while p combines
  auto gatherTap = [&](int kk, int buf) {
    uint4 dA[4], dB[4];
    float wgA[4], wgB[4];
    loadPos(kk, 0 * 16 + hwid, dA, wgA);
    loadPos(kk, 1 * 16 + hwid, dB, wgB);
    *(uint4*)&vbraw[buf][widxP(0 * 16 + hwid)] = combineF16(dA, wgA);
    loadPos(kk, 2 * 16 + hwid, dA, wgA);
    *(uint4*)&vbraw[buf][widxP(1 * 16 + hwid)] = combineF16(dB, wgB);
    loadPos(kk, 3 * 16 + hwid, dB, wgB);
    *(uint4*)&vbraw[buf][widxP(2 * 16 + hwid)] = combineF16(dA, wgA);
    *(uint4*)&vbraw[buf][widxP(3 * 16 + hwid)] = combineF16(dB, wgB);
  };

  // ======== Phase A: 3 row-copies, 3 GEMM epochs (9 shifts) + mask conv ========
  f32x4 aom = (f32x4)0.f;
  const int m0 = w >> 2, nt0 = w & 3;
  const int o0 = w << 5;
  f32x4 acc[2][4];   // mask conv first, then reused for deform
  #pragma unroll
  for (int mt = 0; mt < 2; mt++)
    #pragma unroll
    for (int nt = 0; nt < 4; nt++) acc[mt][nt] = (f32x4)0.f;
  ushort* mws = (ushort*)(ws + M_WS);
  float* sme = ws + SMEAN_WS + b * 256;

  stageRow(h - 1, 0);
  __syncthreads();
  for (int e = 0; e < 3; e++) {
    const int buf = (e == 1) ? 1 : 0;   // e0: row h-1, e1: row h, e2: row h+1
    {
      const int bnA = nt0 * 16 + fr;
      #pragma unroll
      for (int s3 = 0; s3 < 3; s3++) {
        int s = e * 3 + s3;
        const ushort* wp = wom + (size_t)s * 8192;
        int pcol = bnA + s3;
        for (int ks = 0; ks < 8; ks++) {
          short8 af = *(const short8*)(wp + (m0 * 16 + fr) * 256 + ks * 32 + fq * 8);
          uint idx = (uint)pcol * 128u + (((uint)(ks * 16 + fq * 4)) ^ ((uint)(pcol & 7) << 2));
          short8 bf = *(const short8*)&vbraw[buf][idx];
          aom = __builtin_amdgcn_mfma_f32_16x16x32_f16(af, bf, aom, 0, 0, 0);
        }
      }
    }
    if (e == 1) {   // mask 1x1 conv rides the row-h buffer (pcol = n+1)
      const ushort* wt9 = wt2 + (size_t)9 * 65536;
      __builtin_amdgcn_s_setprio(1);
      for (int ks = 0; ks < 8; ks++) {
        short8 af0 = *(const short8*)(wt9 + (o0 + fr) * 256 + ks * 32 + fq * 8);
        short8 af1 = *(const short8*)(wt9 + (o0 + 16 + fr) * 256 + ks * 32 + fq * 8);
        #pragma unroll
        for (int nt = 0; nt < 4; nt++) {
          int pcol = nt * 16 + fr + 1;
          uint idx = (uint)pcol * 128u + (((uint)(ks * 16 + fq * 4)) ^ ((uint)(pcol & 7) << 2));
          short8 bf = *(const short8*)&vbraw[1][idx];
          acc[0][nt] = __builtin_amdgcn_mfma_f32_16x16x32_f16(af0, bf, acc[0][nt], 0, 0, 0);
          acc[1][nt] = __builtin_amdgcn_mfma_f32_16x16x32_f16(af1, bf, acc[1][nt], 0, 0, 0);
        }
      }
      __builtin_amdgcn_s_setprio(0);
    }
    if (e == 0)      stageRow(h, 1);
    else if (e == 1) stageRow(h + 1, 0);
    else {
      // mask epilogue (acc holds mask conv; reset after)
      #pragma unroll
      for (int mt = 0; mt < 2; mt++)
        #pragma unroll
        for (int r = 0; r < 4; r++) {
          int o = o0 + mt * 16 + fq * 4 + r;
          float bm = b_mask[o];
          ushort* mp = mws + (size_t)(b * C_ + o) * HWSZ + h * 64;
          #pragma unroll
          for (int nt = 0; nt < 4; nt++) {
            float mv = fminf(fmaxf((acc[mt][nt][r] + bm) * (1.f / 6.f) + 0.5f, 0.f), 1.f);
            mp[nt * 16 + fr] = f2h(mv);
            acc[mt][nt][r] = 0.f;
          }
        }
      // aom epilogue -> packed records omr[kk][n] = {dy, dx, md, -}
      #pragma unroll
      for (int r = 0; r < 4; r++) {
        int o = m0 * 16 + fq * 4 + r;
        int nn = nt0 * 16 + fr;
        if (o < 18) {
          omrf[(o >> 1) * 256 + nn * 4 + (o & 1)] = aom[r] + b_off[o];
        } else if (o < 27) {
          float v = aom[r] + b_mod[o - 18];
          omrf[(o - 18) * 256 + nn * 4 + 2] = 2.f / (1.f + expf(-v));
        }
      }
    }
    __syncthreads();
  }

  // ======== Phase B: 9 deform taps, dbuf single-barrier ========
  gatherTap(0, 1);    // buf1 free (last read in epoch e=1)
  __syncthreads();
  for (int kk = 0; kk < 9; kk++) {
    const int cur = (kk & 1) ^ 1;
    const ushort* wtap = wt2 + (size_t)kk * 65536;
    __builtin_amdgcn_s_setprio(1);
    for (int ks = 0; ks < 8; ks++) {
      short8 af0 = *(const short8*)(wtap + (o0 + fr) * 256 + ks * 32 + fq * 8);
      short8 af1 = *(const short8*)(wtap + (o0 + 16 + fr) * 256 + ks * 32 + fq * 8);
      #pragma unroll
      for (int nt = 0; nt < 4; nt++) {
        int bn = nt * 16 + fr;
        uint idx = (uint)bn * 128u + (((uint)(ks * 16 + fq * 4)) ^ ((uint)(bn & 7) << 2));
        short8 bf = *(const short8*)&vbraw[cur][idx];
        acc[0][nt] = __builtin_amdgcn_mfma_f32_16x16x32_f16(af0, bf, acc[0][nt], 0, 0, 0);
        acc[1][nt] = __builtin_amdgcn_mfma_f32_16x16x32_f16(af1, bf, acc[1][nt], 0, 0, 0);
      }
    }
    __builtin_amdgcn_s_setprio(0);
    if (kk < 8) {
      gatherTap(kk + 1, cur ^ 1);
      __syncthreads();
    }
  }

  // f epilogue + fused SE partial sums
  #pragma unroll
  for (int mt = 0; mt < 2; mt++)
    #pragma unroll
    for (int r = 0; r < 4; r++) {
      int o = o0 + mt * 16 + fq * 4 + r;
      float bo = b_reg[o];
      float* op = out + (size_t)(b * C_ + o) * HWSZ + h * 64;
      float so = 0.f;
      #pragma unroll
      for (int nt = 0; nt < 4; nt++) {
        float fv = acc[mt][nt][r] + bo;
        op[nt * 16 + fr] = fv;
        so += fv;
      }
      so += __shfl_xor(so, 1);
      so += __shfl_xor(so, 2);
      so += __shfl_xor(so, 4);
      so += __shfl_xor(so, 8);
      if (fr == 0) atomicAdd(&sme[o], so);
    }
}

// ---------------- k4: SE MLP, one block per batch ----------------
__global__ __launch_bounds__(256) void k4_se(
    const float* __restrict__ w_se1, const float* __restrict__ b_se1,
    const float* __restrict__ w_se2, const float* __restrict__ b_se2,
    float* __restrict__ ws) {
  __shared__ float sm[256];
  __shared__ float s1[64];
  int b = blockIdx.x;
  int t = threadIdx.x;
  sm[t] = ws[SMEAN_WS + b * 256 + t] * (1.f / HWSZ);
  __syncthreads();
  if (t < 64) {
    float a = b_se1[t];
    for (int c = 0; c < 256; c++) a += sm[c] * w_se1[t * 256 + c];
    s1[t] = fmaxf(a, 0.f);
  }
  __syncthreads();
  {
    float a = b_se2[t];
    for (int cr = 0; cr < 64; cr++) a += s1[cr] * w_se2[t * 64 + cr];
    ws[SSCALE_WS + b * 256 + t] = 1.f / (1.f + expf(-a));
  }
}

// ---------------- k5: final combine: out = f*s*m + x ----------------
__global__ __launch_bounds__(256) void k5_final(const float* __restrict__ x,
                                                const float* __restrict__ ws,
                                                float* __restrict__ out) {
  const ushort* mws = (const ushort*)(ws + M_WS);
  int i4 = blockIdx.x * 256 + threadIdx.x;
  const int total = B_ * C_ * HWSZ / 4;
  for (; i4 < total; i4 += gridDim.x * 256) {
    int i = i4 * 4;
    int bc = i >> 12;
    float s = ws[SSCALE_WS + bc];
    float4 f = *(const float4*)&out[i];
    uint2 mu = *(const uint2*)&mws[i];
    float4 xv = *(const float4*)&x[i];
    float2 ma = __half22float2(u2h(mu.x));
    float2 mb = __half22float2(u2h(mu.y));
    float4 r;
    r.x = f.x * s * ma.x + xv.x;
    r.y = f.y * s * ma.y + xv.y;
    r.z = f.z * s * mb.x + xv.z;
    r.w = f.w * s * mb.y + xv.w;
    *(float4*)&out[i] = r;
  }
}

extern "C" void kernel_launch(void* const* d_in, const int* in_sizes, int n_in,
                              void* d_out, int out_size, void* d_ws, size_t ws_size,
                              hipStream_t stream) {
  const float* x      = (const float*)d_in[0];
  const float* w_off  = (const float*)d_in[1];
  const float* b_off  = (const float*)d_in[2];
  const float* w_mod  = (const float*)d_in[3];
  const float* b_mod  = (const float*)d_in[4];
  const float* w_reg  = (const float*)d_in[5];
  const float* b_reg  = (const float*)d_in[6];
  const float* w_se1  = (const float*)d_in[7];
  const float* b_se1  = (const float*)d_in[8];
  const float* w_se2  = (const float*)d_in[9];
  const float* b_se2  = (const float*)d_in[10];
  const float* w_mask = (const float*)d_in[11];
  const float* b_mask = (const float*)d_in[12];
  float* out = (float*)d_out;
  float* ws  = (float*)d_ws;

  k0_weights<<<dim3(2856), dim3(256), 0, stream>>>(w_reg, w_mask, w_off, w_mod, ws);
  k0b_nhwc<<<dim3(512), dim3(256), 0, stream>>>(x, ws);
  k2_fused<<<dim3(512), dim3(512), 0, stream>>>(b_off, b_mod, b_reg, b_mask, ws, out);
  k4_se<<<dim3(8), dim3(256), 0, stream>>>(w_se1, b_se1, w_se2, b_se2, ws);
  k5_final<<<dim3(2048), dim3(256), 0, stream>>>(x, ws, out);
}

// Round 15
// 180.234 us; speedup vs baseline: 1.3532x; 1.0150x over previous
//
#include <hip/hip_runtime.h>
#include <hip/hip_fp16.h>
#include <math.h>

#define HWSZ 4096
#define C_ 256
#define B_ 8

// ws layout (float offsets)
#define M_WS      0          // mask f16: 8*256*4096 ushort = 4194304 floats
#define XB_WS     4194304    // x f16 NHWC [b][hw][c]: 4194304 floats
#define WT2_WS    8388608    // (10*65536 + 9*32*256) ushort
#define SMEAN_WS  8753152    // 2048 (f channel sums)
#define SSCALE_WS 8755200    // 2048

typedef __attribute__((ext_vector_type(8))) short short8;
typedef __attribute__((ext_vector_type(4))) float f32x4;

__device__ __forceinline__ ushort f2h(float a) {
  __half h = __float2half(a);
  return *reinterpret_cast<ushort*>(&h);
}
__device__ __forceinline__ uint hpk2(float a, float b) {
  return (uint)f2h(a) | ((uint)f2h(b) << 16);
}
__device__ __forceinline__ uint h2u(__half2 h) { return *reinterpret_cast<uint*>(&h); }
__device__ __forceinline__ __half2 u2h(uint u) { return *reinterpret_cast<__half2*>(&u); }
__device__ __forceinline__ __half2 hi2h2(uint u) {   // broadcast upper-16 half
  ushort us = (ushort)(u >> 16);
  __half h = *reinterpret_cast<__half*>(&us);
  return __half2half2(h);
}

// ---------------- k0: weights -> f16 (+ zero smean) ----------------
__global__ __launch_bounds__(256) void k0_weights(
    const float* __restrict__ w_reg, const float* __restrict__ w_mask,
    const float* __restrict__ w_off, const float* __restrict__ w_mod,
    float* __restrict__ ws) {
  int i = blockIdx.x * 256 + threadIdx.x;
  const int nwt = 10 * 65536;
  const int total = nwt + 9 * 32 * 256;   // 729088
  if (i >= total) {
    int z = i - total;
    if (z < 2048) ws[SMEAN_WS + z] = 0.f;
    return;
  }
  float v;
  if (i < 9 * 65536) {
    int kk = i >> 16, o = (i >> 8) & 255, c = i & 255;
    v = w_reg[(o * C_ + c) * 9 + kk];
  } else if (i < nwt) {
    v = w_mask[i - 9 * 65536];
  } else {
    int e = i - nwt;
    int s = e >> 13, r = e & 8191;
    int o2 = r >> 8, c = r & 255;
    if (o2 < 18)      v = w_off[(o2 * C_ + c) * 9 + s];
    else if (o2 < 27) v = w_mod[((o2 - 18) * C_ + c) * 9 + s];
    else              v = 0.f;
  }
  ((ushort*)(ws + WT2_WS))[i] = f2h(v);
}

// ---------------- k0b: x NCHW f32 -> NHWC f16 ----------------
__global__ __launch_bounds__(256) void k0b_nhwc(const float* __restrict__ x,
                                                float* __restrict__ ws) {
  __shared__ float tile[64][65];
  int b = blockIdx.x >> 6, hw0 = (blockIdx.x & 63) << 6;
  int t = threadIdx.x;
  uint* xb = (uint*)(ws + XB_WS) + ((size_t)b << 19);
  int rr = t >> 6, cc = t & 63;
  int e = t & 7, hwp = t >> 3;
  for (int cg = 0; cg < 4; cg++) {
    __syncthreads();
    const float* xp = x + ((size_t)(b * 256 + cg * 64 + rr)) * HWSZ + hw0 + cc;
    #pragma unroll
    for (int r0 = 0; r0 < 64; r0 += 4)
      tile[r0 + rr][cc] = xp[(size_t)r0 * HWSZ];
    __syncthreads();
    #pragma unroll
    for (int h2 = 0; h2 < 2; h2++) {
      int hw_l = h2 * 32 + hwp;
      int c2 = e * 8;
      uint4 val;
      val.x = hpk2(tile[c2][hw_l], tile[c2 + 1][hw_l]);
      val.y = hpk2(tile[c2 + 2][hw_l], tile[c2 + 3][hw_l]);
      val.z = hpk2(tile[c2 + 4][hw_l], tile[c2 + 5][hw_l]);
      val.w = hpk2(tile[c2 + 6][hw_l], tile[c2 + 7][hw_l]);
      *(uint4*)&xb[(size_t)(hw0 + hw_l) * 128 + cg * 32 + e * 4] = val;
    }
  }
}

// ---------------- k2: r13 structure + packed gather-record table ----------------
// 512 thr (8 waves) per (b,h). Phase A: 3 row-copies + 3 GEMM epochs (9 shifts) + mask
// conv riding row-h. Record table: per (tap,n,corner) uint {idx | f16wgt<<16} built once
// in-place in omrf. Phase B: 9 dbuf gather/GEMM epochs, f16 MFMA, depth-2 gather.
__global__ __launch_bounds__(512, 4) void k2_fused(
    const float* __restrict__ b_off, const float* __restrict__ b_mod,
    const float* __restrict__ b_reg, const float* __restrict__ b_mask,
    float* __restrict__ ws, float* __restrict__ out) {
  __shared__ uint vbraw[2][66 * 128];   // 67.6 KB: padded rows (A) / dbuf taps (B)
  __shared__ float omrf[9 * 64 * 4];    // 9 KB: {dy,dx,md,-} then packed records

  int bl = ((blockIdx.x & 7) << 6) | (blockIdx.x >> 3);   // XCD k -> image k
  int b = bl >> 6, h = bl & 63;
  int t = threadIdx.x;
  int lane = t & 63, w = t >> 6;
  const int hwid = t >> 5;                   // half-wave id 0..15
  const int cl = lane & 31;                  // channel chunk (8 ch)
  const ushort* xb2 = (const ushort*)(ws + XB_WS) + ((size_t)b << 20);
  const ushort* wt2 = (const ushort*)(ws + WT2_WS);
  const ushort* wom = wt2 + 10 * 65536;
  const int fr = lane & 15, fq = lane >> 4;

  auto widxP = [&](int pcol) -> uint {
    return (uint)pcol * 128u + (((uint)cl * 4u) ^ ((uint)(pcol & 7) << 2));
  };
  auto stageRow = [&](int row, int buf) {
    bool rv = ((unsigned)row < 64u);
    #pragma unroll
    for (int p = 0; p < 4; p++) {
      int pcol = p * 16 + hwid;
      int col = pcol - 1;
      uint4 v = make_uint4(0, 0, 0, 0);
      if (rv && ((unsigned)col < 64u))
        v = *(const uint4*)(xb2 + ((size_t)(row * 64 + col)) * 256 + cl * 8);
      *(uint4*)&vbraw[buf][widxP(pcol)] = v;
    }
    if (hwid < 2) {
      int pcol = 64 + hwid;
      int col = pcol - 1;
      uint4 v = make_uint4(0, 0, 0, 0);
      if (rv && col < 64)
        v = *(const uint4*)(xb2 + ((size_t)(row * 64 + col)) * 256 + cl * 8);
      *(uint4*)&vbraw[buf][widxP(pcol)] = v;
    }
  };
  // loadPos: 1 ds_read_b128 -> 4 packed records -> 4 corner loads
  auto loadPos = [&](int kk, int nl, uint4* d, __half2* wv) {
    const uint4 rc = *(const uint4*)&omrf[(kk * 64 + nl) * 4];
    d[0] = *(const uint4*)(xb2 + (size_t)(rc.x & 0xffffu) * 256 + cl * 8);
    d[1] = *(const uint4*)(xb2 + (size_t)(rc.y & 0xffffu) * 256 + cl * 8);
    d[2] = *(const uint4*)(xb2 + (size_t)(rc.z & 0xffffu) * 256 + cl * 8);
    d[3] = *(const uint4*)(xb2 + (size_t)(rc.w & 0xffffu) * 256 + cl * 8);
    wv[0] = hi2h2(rc.x); wv[1] = hi2h2(rc.y);
    wv[2] = hi2h2(rc.z); wv[3] = hi2h2(rc.w);
  };
  auto combineF16 = [&](const uint4* d, const __half2* wv) -> uint4 {
    __half2 a0 = __float2half2_rn(0.f), a1 = a0, a2 = a0, a3 = a0;
    #pragma unroll
    for (int cr = 0; cr < 4; cr++) {
      a0 = __hfma2(wv[cr], u2h(d[cr].x), a0);
      a1 = __hfma2(wv[cr], u2h(d[cr].y), a1);
      a2 = __hfma2(wv[cr], u2h(d[cr].z), a2);
      a3 = __hfma2(wv[cr], u2h(d[cr].w), a3);
    }
    return make_uint4(h2u(a0), h2u(a1), h2u(a2), h2u(a3));
  };
  auto gatherTap = [&](int kk, int buf) {
    uint4 dA[4], dB[4];
    __half2 wA[4], wB[4];
    loadPos(kk, 0 * 16 + hwid, dA, wA);
    loadPos(kk, 1 * 16 + hwid, dB, wB);
    *(uint4*)&vbraw[buf][widxP(0 * 16 + hwid)] = combineF16(dA, wA);
    loadPos(kk, 2 * 16 + hwid, dA, wA);
    *(uint4*)&vbraw[buf][widxP(1 * 16 + hwid)] = combineF16(dB, wB);
    loadPos(kk, 3 * 16 + hwid, dB, wB);
    *(uint4*)&vbraw[buf][widxP(2 * 16 + hwid)] = combineF16(dA, wA);
    *(uint4*)&vbraw[buf][widxP(3 * 16 + hwid)] = combineF16(dB, wB);
  };

  // ======== Phase A: 3 row-copies, 3 GEMM epochs (9 shifts) + mask conv ========
  f32x4 aom = (f32x4)0.f;
  const int m0 = w >> 2, nt0 = w & 3;
  const int o0 = w << 5;
  f32x4 acc[2][4];   // mask conv first, then reused for deform
  #pragma unroll
  for (int mt = 0; mt < 2; mt++)
    #pragma unroll
    for (int nt = 0; nt < 4; nt++) acc[mt][nt] = (f32x4)0.f;
  ushort* mws = (ushort*)(ws + M_WS);
  float* sme = ws + SMEAN_WS + b * 256;

  stageRow(h - 1, 0);
  __syncthreads();
  for (int e = 0; e < 3; e++) {
    const int buf = (e == 1) ? 1 : 0;   // e0: row h-1, e1: row h, e2: row h+1
    {
      const int bnA = nt0 * 16 + fr;
      #pragma unroll
      for (int s3 = 0; s3 < 3; s3++) {
        int s = e * 3 + s3;
        const ushort* wp = wom + (size_t)s * 8192;
        int pcol = bnA + s3;
        for (int ks = 0; ks < 8; ks++) {
          short8 af = *(const short8*)(wp + (m0 * 16 + fr) * 256 + ks * 32 + fq * 8);
          uint idx = (uint)pcol * 128u + (((uint)(ks * 16 + fq * 4)) ^ ((uint)(pcol & 7) << 2));
          short8 bf = *(const short8*)&vbraw[buf][idx];
          aom = __builtin_amdgcn_mfma_f32_16x16x32_f16(af, bf, aom, 0, 0, 0);
        }
      }
    }
    if (e == 1) {   // mask 1x1 conv rides the row-h buffer (pcol = n+1)
      const ushort* wt9 = wt2 + (size_t)9 * 65536;
      __builtin_amdgcn_s_setprio(1);
      for (int ks = 0; ks < 8; ks++) {
        short8 af0 = *(const short8*)(wt9 + (o0 + fr) * 256 + ks * 32 + fq * 8);
        short8 af1 = *(const short8*)(wt9 + (o0 + 16 + fr) * 256 + ks * 32 + fq * 8);
        #pragma unroll
        for (int nt = 0; nt < 4; nt++) {
          int pcol = nt * 16 + fr + 1;
          uint idx = (uint)pcol * 128u + (((uint)(ks * 16 + fq * 4)) ^ ((uint)(pcol & 7) << 2));
          short8 bf = *(const short8*)&vbraw[1][idx];
          acc[0][nt] = __builtin_amdgcn_mfma_f32_16x16x32_f16(af0, bf, acc[0][nt], 0, 0, 0);
          acc[1][nt] = __builtin_amdgcn_mfma_f32_16x16x32_f16(af1, bf, acc[1][nt], 0, 0, 0);
        }
      }
      __builtin_amdgcn_s_setprio(0);
    }
    if (e == 0)      stageRow(h, 1);
    else if (e == 1) stageRow(h + 1, 0);
    else {
      // mask epilogue (acc holds mask conv; reset after)
      #pragma unroll
      for (int mt = 0; mt < 2; mt++)
        #pragma unroll
        for (int r = 0; r < 4; r++) {
          int o = o0 + mt * 16 + fq * 4 + r;
          float bm = b_mask[o];
          ushort* mp = mws + (size_t)(b * C_ + o) * HWSZ + h * 64;
          #pragma unroll
          for (int nt = 0; nt < 4; nt++) {
            float mv = fminf(fmaxf((acc[mt][nt][r] + bm) * (1.f / 6.f) + 0.5f, 0.f), 1.f);
            mp[nt * 16 + fr] = f2h(mv);
            acc[mt][nt][r] = 0.f;
          }
        }
      // aom epilogue -> omrf[kk][n] = {dy, dx, md, -}
      #pragma unroll
      for (int r = 0; r < 4; r++) {
        int o = m0 * 16 + fq * 4 + r;
        int nn = nt0 * 16 + fr;
        if (o < 18) {
          omrf[(o >> 1) * 256 + nn * 4 + (o & 1)] = aom[r] + b_off[o];
        } else if (o < 27) {
          float v = aom[r] + b_mod[o - 18];
          omrf[(o - 18) * 256 + nn * 4 + 2] = 2.f / (1.f + expf(-v));
        }
      }
    }
    __syncthreads();
  }

  // ======== build packed record table in-place (once) ========
  // omrf float4 {dy,dx,md,-} -> uint4 { idx(ushort) | f16wgt << 16 } x 4 corners
  for (int e2 = t; e2 < 576; e2 += 512) {
    int kk = e2 / 64, nl = e2 - kk * 64;
    const float4 rec = *(const float4*)&omrf[e2 * 4];
    float dy = rec.x, dx = rec.y, md = rec.z;
    float py = (float)(h + kk / 3 - 1) + dy;
    float px = (float)(nl + kk % 3 - 1) + dx;
    float fy = floorf(py), fx = floorf(px);
    float ly = py - fy, lx = px - fx;
    int y0 = (int)fy, x0 = (int)fx;
    int y1 = y0 + 1, x1 = x0 + 1;
    float vy0 = ((unsigned)y0 < 64u) ? 1.f : 0.f;
    float vy1 = ((unsigned)y1 < 64u) ? 1.f : 0.f;
    float vx0 = ((unsigned)x0 < 64u) ? 1.f : 0.f;
    float vx1 = ((unsigned)x1 < 64u) ? 1.f : 0.f;
    int cy0 = min(max(y0, 0), 63), cy1 = min(max(y1, 0), 63);
    int cx0 = min(max(x0, 0), 63), cx1 = min(max(x1, 0), 63);
    uint4 pk;
    pk.x = (uint)(cy0 * 64 + cx0) | ((uint)f2h((1.f - ly) * (1.f - lx) * md * vy0 * vx0) << 16);
    pk.y = (uint)(cy0 * 64 + cx1) | ((uint)f2h((1.f - ly) * lx * md * vy0 * vx1) << 16);
    pk.z = (uint)(cy1 * 64 + cx0) | ((uint)f2h(ly * (1.f - lx) * md * vy1 * vx0) << 16);
    pk.w = (uint)(cy1 * 64 + cx1) | ((uint)f2h(ly * lx * md * vy1 * vx1) << 16);
    *(uint4*)&omrf[e2 * 4] = pk;
  }
  __syncthreads();

  // ======== Phase B: 9 deform taps, dbuf single-barrier ========
  gatherTap(0, 1);    // buf1 free (last read in epoch e=1)
  __syncthreads();
  for (int kk = 0; kk < 9; kk++) {
    const int cur = (kk & 1) ^ 1;
    const ushort* wtap = wt2 + (size_t)kk * 65536;
    __builtin_amdgcn_s_setprio(1);
    for (int ks = 0; ks < 8; ks++) {
      short8 af0 = *(const short8*)(wtap + (o0 + fr) * 256 + ks * 32 + fq * 8);
      short8 af1 = *(const short8*)(wtap + (o0 + 16 + fr) * 256 + ks * 32 + fq * 8);
      #pragma unroll
      for (int nt = 0; nt < 4; nt++) {
        int bn = nt * 16 + fr;
        uint idx = (uint)bn * 128u + (((uint)(ks * 16 + fq * 4)) ^ ((uint)(bn & 7) << 2));
        short8 bf = *(const short8*)&vbraw[cur][idx];
        acc[0][nt] = __builtin_amdgcn_mfma_f32_16x16x32_f16(af0, bf, acc[0][nt], 0, 0, 0);
        acc[1][nt] = __builtin_amdgcn_mfma_f32_16x16x32_f16(af1, bf, acc[1][nt], 0, 0, 0);
      }
    }
    __builtin_amdgcn_s_setprio(0);
    if (kk < 8) {
      gatherTap(kk + 1, cur ^ 1);
      __syncthreads();
    }
  }

  // f epilogue + fused SE partial sums
  #pragma unroll
  for (int mt = 0; mt < 2; mt++)
    #pragma unroll
    for (int r = 0; r < 4; r++) {
      int o = o0 + mt * 16 + fq * 4 + r;
      float bo = b_reg[o];
      float* op = out + (size_t)(b * C_ + o) * HWSZ + h * 64;
      float so = 0.f;
      #pragma unroll
      for (int nt = 0; nt < 4; nt++) {
        float fv = acc[mt][nt][r] + bo;
        op[nt * 16 + fr] = fv;
        so += fv;
      }
      so += __shfl_xor(so, 1);
      so += __shfl_xor(so, 2);
      so += __shfl_xor(so, 4);
      so += __shfl_xor(so, 8);
      if (fr == 0) atomicAdd(&sme[o], so);
    }
}

// ---------------- k4: SE MLP, one block per batch ----------------
__global__ __launch_bounds__(256) void k4_se(
    const float* __restrict__ w_se1, const float* __restrict__ b_se1,
    const float* __restrict__ w_se2, const float* __restrict__ b_se2,
    float* __restrict__ ws) {
  __shared__ float sm[256];
  __shared__ float s1[64];
  int b = blockIdx.x;
  int t = threadIdx.x;
  sm[t] = ws[SMEAN_WS + b * 256 + t] * (1.f / HWSZ);
  __syncthreads();
  if (t < 64) {
    float a = b_se1[t];
    for (int c = 0; c < 256; c++) a += sm[c] * w_se1[t * 256 + c];
    s1[t] = fmaxf(a, 0.f);
  }
  __syncthreads();
  {
    float a = b_se2[t];
    for (int cr = 0; cr < 64; cr++) a += s1[cr] * w_se2[t * 64 + cr];
    ws[SSCALE_WS + b * 256 + t] = 1.f / (1.f + expf(-a));
  }
}

// ---------------- k5: final combine: out = f*s*m + x ----------------
__global__ __launch_bounds__(256) void k5_final(const float* __restrict__ x,
                                                const float* __restrict__ ws,
                                                float* __restrict__ out) {
  const ushort* mws = (const ushort*)(ws + M_WS);
  int i4 = blockIdx.x * 256 + threadIdx.x;
  const int total = B_ * C_ * HWSZ / 4;
  for (; i4 < total; i4 += gridDim.x * 256) {
    int i = i4 * 4;
    int bc = i >> 12;
    float s = ws[SSCALE_WS + bc];
    float4 f = *(const float4*)&out[i];
    uint2 mu = *(const uint2*)&mws[i];
    float4 xv = *(const float4*)&x[i];
    float2 ma = __half22float2(u2h(mu.x));
    float2 mb = __half22float2(u2h(mu.y));
    float4 r;
    r.x = f.x * s * ma.x + xv.x;
    r.y = f.y * s * ma.y + xv.y;
    r.z = f.z * s * mb.x + xv.z;
    r.w = f.w * s * mb.y + xv.w;
    *(float4*)&out[i] = r;
  }
}

extern "C" void kernel_launch(void* const* d_in, const int* in_sizes, int n_in,
                              void* d_out, int out_size, void* d_ws, size_t ws_size,
                              hipStream_t stream) {
  const float* x      = (const float*)d_in[0];
  const float* w_off  = (const float*)d_in[1];
  const float* b_off  = (const float*)d_in[2];
  const float* w_mod  = (const float*)d_in[3];
  const float* b_mod  = (const float*)d_in[4];
  const float* w_reg  = (const float*)d_in[5];
  const float* b_reg  = (const float*)d_in[6];
  const float* w_se1  = (const float*)d_in[7];
  const float* b_se1  = (const float*)d_in[8];
  const float* w_se2  = (const float*)d_in[9];
  const float* b_se2  = (const float*)d_in[10];
  const float* w_mask = (const float*)d_in[11];
  const float* b_mask = (const float*)d_in[12];
  float* out = (float*)d_out;
  float* ws  = (float*)d_ws;

  k0_weights<<<dim3(2856), dim3(256), 0, stream>>>(w_reg, w_mask, w_off, w_mod, ws);
  k0b_nhwc<<<dim3(512), dim3(256), 0, stream>>>(x, ws);
  k2_fused<<<dim3(512), dim3(512), 0, stream>>>(b_off, b_mod, b_reg, b_mask, ws, out);
  k4_se<<<dim3(8), dim3(256), 0, stream>>>(w_se1, b_se1, w_se2, b_se2, ws);
  k5_final<<<dim3(2048), dim3(256), 0, stream>>>(x, ws, out);
}